// Round 2
// baseline (285.913 us; speedup 1.0000x reference)
//
#include <hip/hip_runtime.h>
#include <math.h>

#define LRELU 0.2f
#define BSH 7                  // 128 dsts per bucket
#define BSZ (1 << BSH)
#define CH 8192                // edges per phase-1 block

typedef __attribute__((ext_vector_type(8))) short bf16x8;
typedef __attribute__((ext_vector_type(4))) float f32x4;

static __device__ __forceinline__ float bf2f(unsigned int u16) {
    union { unsigned int i; float f; } c; c.i = u16 << 16; return c.f;
}
static __device__ __forceinline__ unsigned short f2bf(float f) {
    union { float f; unsigned int i; } c; c.f = f;
    unsigned int x = c.i;
    return (unsigned short)((x + 0x7fffu + ((x >> 16) & 1u)) >> 16);  // RNE
}

// ---------------- CSR build (bucket-centric) ----------

__global__ __launch_bounds__(256) void k_bcount(const int* __restrict__ dst, int E,
                                                int NB, int* __restrict__ bcnt) {
    __shared__ int cnt[512];
    int t = threadIdx.x;
    for (int b = t; b < 512; b += 256) cnt[b] = 0;
    __syncthreads();
    int e0 = blockIdx.x * CH;
    int e1 = e0 + CH; if (e1 > E) e1 = E;
    for (int i = e0 + t; i < e1; i += 256) atomicAdd(&cnt[dst[i] >> BSH], 1);
    __syncthreads();
    for (int b = t; b < NB; b += 256) {
        int c = cnt[b];
        if (c) atomicAdd(&bcnt[b], c);
    }
}

__global__ __launch_bounds__(64) void k_bscan(const int* __restrict__ bcnt, int NB,
                                              int* __restrict__ boff,
                                              int* __restrict__ bcur) {
    int lane = threadIdx.x;
    int run = 0;
    for (int base = 0; base < NB; base += 64) {
        int v = (base + lane < NB) ? bcnt[base + lane] : 0;
        int inc = v;
#pragma unroll
        for (int off = 1; off < 64; off <<= 1) {
            int t = __shfl_up(inc, off, 64);
            if (lane >= off) inc += t;
        }
        if (base + lane < NB) {
            int e = run + inc - v;
            boff[base + lane] = e;
            bcur[base + lane] = e;
        }
        run += __shfl(inc, 63, 64);
    }
    if (lane == 0) boff[NB] = run;
}

__global__ __launch_bounds__(256) void k_binscat1(const int* __restrict__ src,
                                                  const int* __restrict__ dst,
                                                  int E, int NB,
                                                  int* __restrict__ bcur,
                                                  unsigned* __restrict__ pairs) {
    __shared__ int cnt[512];
    __shared__ int lds_d[CH];
    int t = threadIdx.x;
    int e0 = blockIdx.x * CH;
    int e1 = e0 + CH; if (e1 > E) e1 = E;
    int n = e1 - e0;
    for (int b = t; b < 512; b += 256) cnt[b] = 0;
    __syncthreads();
    for (int i = t; i < n; i += 256) {
        int d = dst[e0 + i];
        lds_d[i] = d;
        atomicAdd(&cnt[d >> BSH], 1);
    }
    __syncthreads();
    for (int b = t; b < NB; b += 256) {
        int c = cnt[b];
        cnt[b] = c ? atomicAdd(&bcur[b], c) : 0;
    }
    __syncthreads();
    for (int i = t; i < n; i += 256) {
        int d = lds_d[i];
        int p = atomicAdd(&cnt[d >> BSH], 1);
        pairs[p] = ((unsigned)src[e0 + i] << BSH) | (unsigned)(d & (BSZ - 1));
    }
}

__global__ __launch_bounds__(256) void k_bucket(const int* __restrict__ boff,
                                                const unsigned* __restrict__ pairs,
                                                int N, int* __restrict__ rowptr,
                                                int* __restrict__ col) {
    __shared__ int cnt[BSZ];
    __shared__ int cur[BSZ];
    int t = threadIdx.x;
    int b = blockIdx.x;
    int dlo = b << BSH;
    int dhi = dlo + BSZ; if (dhi > N) dhi = N;
    int nd = dhi - dlo;
    int jb = boff[b], je = boff[b + 1];
    if (t < BSZ) cnt[t] = 0;
    __syncthreads();
    for (int j = jb + t; j < je; j += 256) atomicAdd(&cnt[pairs[j] & (BSZ - 1)], 1);
    __syncthreads();
    if (t < 64) {
        int v0 = cnt[t], v1 = cnt[64 + t];
        int i0 = v0;
#pragma unroll
        for (int off = 1; off < 64; off <<= 1) {
            int q = __shfl_up(i0, off, 64);
            if (t >= off) i0 += q;
        }
        int tot0 = __shfl(i0, 63, 64);
        int i1 = v1;
#pragma unroll
        for (int off = 1; off < 64; off <<= 1) {
            int q = __shfl_up(i1, off, 64);
            if (t >= off) i1 += q;
        }
        int e0x = jb + i0 - v0;
        int e1x = jb + tot0 + i1 - v1;
        cur[t] = e0x;
        cur[64 + t] = e1x;
        if (t < nd) rowptr[dlo + t] = e0x;
        if (64 + t < nd) rowptr[dlo + 64 + t] = e1x;
        if (t == 0 && dhi == N) rowptr[N] = je;
    }
    __syncthreads();
    for (int j = jb + t; j < je; j += 256) {
        unsigned pk = pairs[j];
        int p = atomicAdd(&cur[pk & (BSZ - 1)], 1);
        col[p] = (int)(pk >> BSH);
    }
}

// -------- weight convert/transpose to bf16 + sentinel init --------
__global__ __launch_bounds__(256) void k_cvtW(const float* __restrict__ W1,
                                              const float* __restrict__ W2,
                                              unsigned short* __restrict__ Wt1,
                                              unsigned short* __restrict__ Wt2,
                                              float* __restrict__ s1,
                                              float* __restrict__ s2,
                                              unsigned short* __restrict__ h1b,
                                              unsigned short* __restrict__ gb,
                                              int N) {
    int idx = blockIdx.x * 256 + threadIdx.x;
    if (idx < 16384) {
        int n = idx >> 8, k = idx & 255;
        Wt1[idx] = f2bf(W1[k * 64 + n]);
    } else if (idx < 16384 + 4096) {
        int j = idx - 16384;
        int n = j >> 6, k = j & 63;
        Wt2[j] = f2bf(W2[k * 64 + n]);
    } else if (idx < 20488) {
        s1[(size_t)N * 8 + (idx - 20480)] = -1e30f;       // asrc1 sentinel row
    } else if (idx == 20488) {
        s2[N] = -1e30f;                                    // asrc2 sentinel
    } else if (idx >= 20496 && idx < 20560) {
        h1b[(size_t)N * 64 + (idx - 20496)] = 0;           // Hb sentinel row = 0
    } else if (idx >= 20560 && idx < 20624) {
        gb[(size_t)N * 64 + (idx - 20560)] = 0;            // Gb sentinel row = 0
    }
}

// ---------------- MFMA GEMM1 ----------------
__global__ __launch_bounds__(256) void k_gemm1m(const float* __restrict__ X,
                                                const unsigned short* __restrict__ Wt,
                                                const float* __restrict__ atts,
                                                const float* __restrict__ attd,
                                                int N, unsigned short* __restrict__ Hb,
                                                float* __restrict__ asrc,
                                                float* __restrict__ adst) {
    __shared__ short Xl[64 * 256];
    int t = threadIdx.x, l = t & 63, w = t >> 6;
    int rblk = blockIdx.x * 64;

    int half = l >> 5;
    int c8 = (l & 31) * 8;
#pragma unroll
    for (int i = 0; i < 8; ++i) {
        int rl = w * 16 + i * 2 + half;
        int row = rblk + rl;
        float4 x0 = {0.f, 0.f, 0.f, 0.f}, x1 = {0.f, 0.f, 0.f, 0.f};
        if (row < N) {
            x0 = *reinterpret_cast<const float4*>(X + (size_t)row * 256 + c8);
            x1 = *reinterpret_cast<const float4*>(X + (size_t)row * 256 + c8 + 4);
        }
        bf16x8 p;
        p[0] = (short)f2bf(x0.x); p[1] = (short)f2bf(x0.y);
        p[2] = (short)f2bf(x0.z); p[3] = (short)f2bf(x0.w);
        p[4] = (short)f2bf(x1.x); p[5] = (short)f2bf(x1.y);
        p[6] = (short)f2bf(x1.z); p[7] = (short)f2bf(x1.w);
        int g = (l & 31) ^ (rl & 7);
        *reinterpret_cast<bf16x8*>(&Xl[rl * 256 + g * 8]) = p;
    }

    int m = l & 15, quad = l >> 4;
    int rl = w * 16 + m;
    f32x4 acc0 = {0.f, 0.f, 0.f, 0.f}, acc1 = acc0, acc2 = acc0, acc3 = acc0;
#pragma unroll
    for (int tt = 0; tt < 8; ++tt) {
        int g = (tt * 4 + quad) ^ (m & 7);
        bf16x8 a = *reinterpret_cast<const bf16x8*>(&Xl[rl * 256 + g * 8]);
        int kk = tt * 32 + quad * 8;
        bf16x8 b0 = *reinterpret_cast<const bf16x8*>(&Wt[(0 * 16 + m) * 256 + kk]);
        bf16x8 b1 = *reinterpret_cast<const bf16x8*>(&Wt[(1 * 16 + m) * 256 + kk]);
        bf16x8 b2 = *reinterpret_cast<const bf16x8*>(&Wt[(2 * 16 + m) * 256 + kk]);
        bf16x8 b3 = *reinterpret_cast<const bf16x8*>(&Wt[(3 * 16 + m) * 256 + kk]);
        acc0 = __builtin_amdgcn_mfma_f32_16x16x32_bf16(a, b0, acc0, 0, 0, 0);
        acc1 = __builtin_amdgcn_mfma_f32_16x16x32_bf16(a, b1, acc1, 0, 0, 0);
        acc2 = __builtin_amdgcn_mfma_f32_16x16x32_bf16(a, b2, acc2, 0, 0, 0);
        acc3 = __builtin_amdgcn_mfma_f32_16x16x32_bf16(a, b3, acc3, 0, 0, 0);
    }

    int r0 = rblk + w * 16;
    f32x4 accs[4] = {acc0, acc1, acc2, acc3};
#pragma unroll
    for (int nt = 0; nt < 4; ++nt) {
        int cn = nt * 16 + m;
        float av_s = atts[cn], av_d = attd[cn];
#pragma unroll
        for (int r = 0; r < 4; ++r) {
            int row = r0 + quad * 4 + r;
            float hv = accs[nt][r];
            if (row < N) Hb[(size_t)row * 64 + cn] = f2bf(hv);
            float vs = hv * av_s, vd = hv * av_d;
            vs += __shfl_xor(vs, 1, 64); vs += __shfl_xor(vs, 2, 64); vs += __shfl_xor(vs, 4, 64);
            vd += __shfl_xor(vd, 1, 64); vd += __shfl_xor(vd, 2, 64); vd += __shfl_xor(vd, 4, 64);
            if ((m & 7) == 0 && row < N) {
                int head = cn >> 3;
                asrc[row * 8 + head] = vs;
                adst[row * 8 + head] = vd;
            }
        }
    }
}

// ---------------- MFMA GEMM2 ----------------
__global__ __launch_bounds__(256) void k_gemm2m(const unsigned short* __restrict__ Xb,
                                                const unsigned short* __restrict__ Wt,
                                                const float* __restrict__ atts,
                                                const float* __restrict__ attd,
                                                int N, unsigned short* __restrict__ Gb,
                                                float* __restrict__ asrc,
                                                float* __restrict__ adst) {
    int t = threadIdx.x, l = t & 63, w = t >> 6;
    int rblk = blockIdx.x * 64;
    int m = l & 15, quad = l >> 4;
    int row = rblk + w * 16 + m;
    int rowc = (row < N) ? row : 0;

    f32x4 acc0 = {0.f, 0.f, 0.f, 0.f}, acc1 = acc0, acc2 = acc0, acc3 = acc0;
#pragma unroll
    for (int tt = 0; tt < 2; ++tt) {
        int kk = tt * 32 + quad * 8;
        bf16x8 a = *reinterpret_cast<const bf16x8*>(&Xb[(size_t)rowc * 64 + kk]);
        bf16x8 b0 = *reinterpret_cast<const bf16x8*>(&Wt[(0 * 16 + m) * 64 + kk]);
        bf16x8 b1 = *reinterpret_cast<const bf16x8*>(&Wt[(1 * 16 + m) * 64 + kk]);
        bf16x8 b2 = *reinterpret_cast<const bf16x8*>(&Wt[(2 * 16 + m) * 64 + kk]);
        bf16x8 b3 = *reinterpret_cast<const bf16x8*>(&Wt[(3 * 16 + m) * 64 + kk]);
        acc0 = __builtin_amdgcn_mfma_f32_16x16x32_bf16(a, b0, acc0, 0, 0, 0);
        acc1 = __builtin_amdgcn_mfma_f32_16x16x32_bf16(a, b1, acc1, 0, 0, 0);
        acc2 = __builtin_amdgcn_mfma_f32_16x16x32_bf16(a, b2, acc2, 0, 0, 0);
        acc3 = __builtin_amdgcn_mfma_f32_16x16x32_bf16(a, b3, acc3, 0, 0, 0);
    }

    int r0 = rblk + w * 16;
    f32x4 accs[4] = {acc0, acc1, acc2, acc3};
#pragma unroll
    for (int r = 0; r < 4; ++r) {
        int orow = r0 + quad * 4 + r;
        float vs = 0.f, vd = 0.f;
#pragma unroll
        for (int nt = 0; nt < 4; ++nt) {
            int cn = nt * 16 + m;
            float hv = accs[nt][r];
            if (orow < N) Gb[(size_t)orow * 64 + cn] = f2bf(hv);
            vs = fmaf(hv, atts[cn], vs);
            vd = fmaf(hv, attd[cn], vd);
        }
#pragma unroll
        for (int off = 1; off < 16; off <<= 1) {
            vs += __shfl_xor(vs, off, 64);
            vd += __shfl_xor(vd, off, 64);
        }
        if (m == 0 && orow < N) { asrc[orow] = vs; adst[orow] = vd; }
    }
}

// ------- Fused gather: 8 dsts per wave (1 dst per 8-lane group) -------
// lane = grp*8 + sub. grp <-> dst, sub <-> head/channel-octet.
// Each lane owns its (head, 8ch) slice: denominator and accumulators are
// lane-private -> NO cross-lane reduction; epilogue uses all 64 lanes.
// Tail edges resolved via sentinel src row N (asrc=-1e30 -> w=0, Hb=0).

__global__ __launch_bounds__(256) void k_gather1(const int* __restrict__ rowptr,
                                                 const int* __restrict__ col,
                                                 const uint4* __restrict__ Hb8,
                                                 const float* __restrict__ asrc,
                                                 const float* __restrict__ adst,
                                                 const float* __restrict__ bias,
                                                 int N,
                                                 unsigned short* __restrict__ outb) {
    int lane = threadIdx.x & 63;
    int wv = threadIdx.x >> 6;
    int grp = lane >> 3, sub = lane & 7;
    int d = blockIdx.x * 32 + wv * 8 + grp;
    int dok = (d < N);
    int dc = dok ? d : 0;
    int jb = rowptr[dc];
    int je = rowptr[dc + 1];
    if (!dok) { jb = 0; je = 0; }
    float adv = dok ? adst[dc * 8 + sub] : 0.f;
    int nit = (je - jb + 3) >> 2;
    int nmax = nit;
    nmax = max(nmax, __shfl_xor(nmax, 8, 64));
    nmax = max(nmax, __shfl_xor(nmax, 16, 64));
    nmax = max(nmax, __shfl_xor(nmax, 32, 64));

    float acc[8] = {0.f, 0.f, 0.f, 0.f, 0.f, 0.f, 0.f, 0.f};
    float denom = 0.f;
    int u = jb;
    for (int it = 0; it < nmax; ++it) {
        int s4[4];
#pragma unroll
        for (int q = 0; q < 4; ++q) {
            int uu = u + q;
            int ok = uu < je;
            int j = ok ? uu : 0;
            int s = __builtin_nontemporal_load(&col[j]);
            s4[q] = ok ? s : N;                 // sentinel row -> w=0, h=0
        }
        float as4[4]; uint4 hv4[4];
#pragma unroll
        for (int q = 0; q < 4; ++q) {
            size_t o = (size_t)s4[q] * 8 + sub;
            as4[q] = asrc[o];
            hv4[q] = Hb8[o];
        }
        __builtin_amdgcn_sched_barrier(0);
#pragma unroll
        for (int q = 0; q < 4; ++q) {
            float e = as4[q] + adv;
            e = (e > 0.f) ? e : LRELU * e;
            float wgt = __expf(e);
            uint4 hv = hv4[q];
            denom += wgt;
            acc[0] = fmaf(wgt, bf2f(hv.x & 0xffffu), acc[0]);
            acc[1] = fmaf(wgt, bf2f(hv.x >> 16), acc[1]);
            acc[2] = fmaf(wgt, bf2f(hv.y & 0xffffu), acc[2]);
            acc[3] = fmaf(wgt, bf2f(hv.y >> 16), acc[3]);
            acc[4] = fmaf(wgt, bf2f(hv.z & 0xffffu), acc[4]);
            acc[5] = fmaf(wgt, bf2f(hv.z >> 16), acc[5]);
            acc[6] = fmaf(wgt, bf2f(hv.w & 0xffffu), acc[6]);
            acc[7] = fmaf(wgt, bf2f(hv.w >> 16), acc[7]);
        }
        u += 4;
    }
    if (dok) {
        float invd = 1.f / (denom + 1e-16f);
        unsigned short pk[8];
#pragma unroll
        for (int c = 0; c < 8; ++c) {
            float v = fmaf(acc[c], invd, bias[sub * 8 + c]);
            v = (v > 0.f) ? v : expm1f(v);
            pk[c] = f2bf(v);
        }
        uint4 pv;
        pv.x = (unsigned)pk[0] | ((unsigned)pk[1] << 16);
        pv.y = (unsigned)pk[2] | ((unsigned)pk[3] << 16);
        pv.z = (unsigned)pk[4] | ((unsigned)pk[5] << 16);
        pv.w = (unsigned)pk[6] | ((unsigned)pk[7] << 16);
        *reinterpret_cast<uint4*>(&outb[(size_t)d * 64 + sub * 8]) = pv;
    }
}

__global__ __launch_bounds__(256) void k_gather2(const int* __restrict__ rowptr,
                                                 const int* __restrict__ col,
                                                 const uint4* __restrict__ Gb8,
                                                 const float* __restrict__ asrc,
                                                 const float* __restrict__ adst,
                                                 const float* __restrict__ bias,
                                                 int N,
                                                 float* __restrict__ out) {
    int lane = threadIdx.x & 63;
    int wv = threadIdx.x >> 6;
    int grp = lane >> 3, sub = lane & 7;
    int d = blockIdx.x * 32 + wv * 8 + grp;
    int dok = (d < N);
    int dc = dok ? d : 0;
    int jb = rowptr[dc];
    int je = rowptr[dc + 1];
    if (!dok) { jb = 0; je = 0; }
    float adv = dok ? adst[dc] : 0.f;
    int nit = (je - jb + 3) >> 2;
    int nmax = nit;
    nmax = max(nmax, __shfl_xor(nmax, 8, 64));
    nmax = max(nmax, __shfl_xor(nmax, 16, 64));
    nmax = max(nmax, __shfl_xor(nmax, 32, 64));

    float acc[8] = {0.f, 0.f, 0.f, 0.f, 0.f, 0.f, 0.f, 0.f};
    float denom = 0.f;
    int u = jb;
    for (int it = 0; it < nmax; ++it) {
        int s4[4];
#pragma unroll
        for (int q = 0; q < 4; ++q) {
            int uu = u + q;
            int ok = uu < je;
            int j = ok ? uu : 0;
            int s = __builtin_nontemporal_load(&col[j]);
            s4[q] = ok ? s : N;
        }
        float as4[4]; uint4 hv4[4];
#pragma unroll
        for (int q = 0; q < 4; ++q) {
            as4[q] = asrc[s4[q]];
            hv4[q] = Gb8[(size_t)s4[q] * 8 + sub];
        }
        __builtin_amdgcn_sched_barrier(0);
#pragma unroll
        for (int q = 0; q < 4; ++q) {
            float e = as4[q] + adv;
            e = (e > 0.f) ? e : LRELU * e;
            float wgt = __expf(e);
            uint4 hv = hv4[q];
            denom += wgt;
            acc[0] = fmaf(wgt, bf2f(hv.x & 0xffffu), acc[0]);
            acc[1] = fmaf(wgt, bf2f(hv.x >> 16), acc[1]);
            acc[2] = fmaf(wgt, bf2f(hv.y & 0xffffu), acc[2]);
            acc[3] = fmaf(wgt, bf2f(hv.y >> 16), acc[3]);
            acc[4] = fmaf(wgt, bf2f(hv.z & 0xffffu), acc[4]);
            acc[5] = fmaf(wgt, bf2f(hv.z >> 16), acc[5]);
            acc[6] = fmaf(wgt, bf2f(hv.w & 0xffffu), acc[6]);
            acc[7] = fmaf(wgt, bf2f(hv.w >> 16), acc[7]);
        }
        u += 4;
    }
    float invd = 1.f / (denom + 1e-16f);
    float v[8];
#pragma unroll
    for (int c = 0; c < 8; ++c) v[c] = fmaf(acc[c], invd, bias[sub * 8 + c]);
    // log_softmax over the 8-lane group (64 channels per dst)
    float m = v[0];
#pragma unroll
    for (int c = 1; c < 8; ++c) m = fmaxf(m, v[c]);
    m = fmaxf(m, __shfl_xor(m, 1, 64));
    m = fmaxf(m, __shfl_xor(m, 2, 64));
    m = fmaxf(m, __shfl_xor(m, 4, 64));
    float se = 0.f;
#pragma unroll
    for (int c = 0; c < 8; ++c) se += __expf(v[c] - m);
    se += __shfl_xor(se, 1, 64);
    se += __shfl_xor(se, 2, 64);
    se += __shfl_xor(se, 4, 64);
    float ls = m + __logf(se);
    if (dok) {
        float4 o0, o1;
        o0.x = v[0] - ls; o0.y = v[1] - ls; o0.z = v[2] - ls; o0.w = v[3] - ls;
        o1.x = v[4] - ls; o1.y = v[5] - ls; o1.z = v[6] - ls; o1.w = v[7] - ls;
        *reinterpret_cast<float4*>(&out[(size_t)d * 64 + sub * 8]) = o0;
        *reinterpret_cast<float4*>(&out[(size_t)d * 64 + sub * 8 + 4]) = o1;
    }
}

// ---------------- launch ----------------

extern "C" void kernel_launch(void* const* d_in, const int* in_sizes, int n_in,
                              void* d_out, int out_size, void* d_ws, size_t ws_size,
                              hipStream_t stream) {
    const float* x   = (const float*)d_in[0];
    const int*   ei  = (const int*)d_in[1];
    const float* W1  = (const float*)d_in[2];
    const float* as1 = (const float*)d_in[3];
    const float* ad1 = (const float*)d_in[4];
    const float* b1  = (const float*)d_in[5];
    const float* W2  = (const float*)d_in[6];
    const float* as2 = (const float*)d_in[7];
    const float* ad2 = (const float*)d_in[8];
    const float* b2  = (const float*)d_in[9];
    float* out = (float*)d_out;

    const int N = in_sizes[0] / 256;
    const int E = in_sizes[1] / 2;
    const int* src = ei;
    const int* dst = ei + E;
    const int NB = (N + BSZ - 1) >> BSH;
    const int nchunk = (E + CH - 1) / CH;

    char* ws = (char*)d_ws;
    size_t off = 0;
    auto alloc = [&](size_t bytes) -> void* {
        void* p = ws + off;
        off = (off + bytes + 255) & ~(size_t)255;
        return p;
    };
    int*      bcnt   = (int*)alloc((size_t)NB * 4);
    int*      boff   = (int*)alloc((size_t)(NB + 1) * 4);
    int*      bcur   = (int*)alloc((size_t)NB * 4);
    int*      rowptr = (int*)alloc((size_t)(N + 1) * 4);
    int*      col    = (int*)alloc((size_t)E * 4);
    unsigned* pairs  = (unsigned*)alloc((size_t)E * 4);
    unsigned short* wt1 = (unsigned short*)alloc(64 * 256 * 2);
    unsigned short* wt2 = (unsigned short*)alloc(64 * 64 * 2);
    unsigned short* h1b = (unsigned short*)alloc((size_t)(N + 1) * 64 * 2);
    float* a_s1   = (float*)alloc(((size_t)N * 8 + 8) * 4);
    float* a_d1   = (float*)alloc((size_t)N * 8 * 4);
    unsigned short* h2b = (unsigned short*)alloc((size_t)N * 64 * 2);
    unsigned short* gb  = (unsigned short*)alloc((size_t)(N + 1) * 64 * 2);
    float* a_s2   = (float*)alloc((size_t)(N + 1) * 4);
    float* a_d2   = (float*)alloc((size_t)N * 4);
    (void)ws_size; (void)n_in; (void)out_size;

    k_cvtW<<<81, 256, 0, stream>>>(W1, W2, wt1, wt2, a_s1, a_s2, h1b, gb, N);

    hipMemsetAsync(bcnt, 0, (size_t)NB * 4, stream);
    k_bcount<<<nchunk, 256, 0, stream>>>(dst, E, NB, bcnt);
    k_bscan<<<1, 64, 0, stream>>>(bcnt, NB, boff, bcur);
    k_binscat1<<<nchunk, 256, 0, stream>>>(src, dst, E, NB, bcur, pairs);
    k_bucket<<<NB, 256, 0, stream>>>(boff, pairs, N, rowptr, col);

    int gblk = (N + 63) / 64;
    k_gemm1m<<<gblk, 256, 0, stream>>>(x, wt1, as1, ad1, N, h1b, a_s1, a_d1);

    int gather_blocks = (N + 31) / 32;
    k_gather1<<<gather_blocks, 256, 0, stream>>>(rowptr, col, (const uint4*)h1b,
                                                 a_s1, a_d1, b1, N, h2b);

    k_gemm2m<<<gblk, 256, 0, stream>>>(h2b, wt2, as2, ad2, N, gb, a_s2, a_d2);

    k_gather2<<<gather_blocks, 256, 0, stream>>>(rowptr, col, (const uint4*)gb,
                                                 a_s2, a_d2, b2, N, out);
}

// Round 3
// 249.877 us; speedup vs baseline: 1.1442x; 1.1442x over previous
//
#include <hip/hip_runtime.h>
#include <math.h>

#define LRELU 0.2f
#define BSH 7                  // 128 dsts per bucket
#define BSZ (1 << BSH)
#define CH 8192                // edges per phase-1 block
#define ECH 2048               // staged edges per gather block (8 KB LDS)
#define GB 6                   // gather batch depth (loads in flight per lane)

typedef __attribute__((ext_vector_type(8))) short bf16x8;
typedef __attribute__((ext_vector_type(4))) float f32x4;

static __device__ __forceinline__ float bf2f(unsigned int u16) {
    union { unsigned int i; float f; } c; c.i = u16 << 16; return c.f;
}
static __device__ __forceinline__ unsigned short f2bf(float f) {
    union { float f; unsigned int i; } c; c.f = f;
    unsigned int x = c.i;
    return (unsigned short)((x + 0x7fffu + ((x >> 16) & 1u)) >> 16);  // RNE
}

// ---------------- CSR build (bucket-centric) ----------

__global__ __launch_bounds__(256) void k_bcount(const int* __restrict__ dst, int E,
                                                int NB, int* __restrict__ bcnt) {
    __shared__ int cnt[512];
    int t = threadIdx.x;
    for (int b = t; b < 512; b += 256) cnt[b] = 0;
    __syncthreads();
    int e0 = blockIdx.x * CH;
    int e1 = e0 + CH; if (e1 > E) e1 = E;
    for (int i = e0 + t; i < e1; i += 256) atomicAdd(&cnt[dst[i] >> BSH], 1);
    __syncthreads();
    for (int b = t; b < NB; b += 256) {
        int c = cnt[b];
        if (c) atomicAdd(&bcnt[b], c);
    }
}

__global__ __launch_bounds__(64) void k_bscan(const int* __restrict__ bcnt, int NB,
                                              int* __restrict__ boff,
                                              int* __restrict__ bcur) {
    int lane = threadIdx.x;
    int run = 0;
    for (int base = 0; base < NB; base += 64) {
        int v = (base + lane < NB) ? bcnt[base + lane] : 0;
        int inc = v;
#pragma unroll
        for (int off = 1; off < 64; off <<= 1) {
            int t = __shfl_up(inc, off, 64);
            if (lane >= off) inc += t;
        }
        if (base + lane < NB) {
            int e = run + inc - v;
            boff[base + lane] = e;
            bcur[base + lane] = e;
        }
        run += __shfl(inc, 63, 64);
    }
    if (lane == 0) boff[NB] = run;
}

__global__ __launch_bounds__(256) void k_binscat1(const int* __restrict__ src,
                                                  const int* __restrict__ dst,
                                                  int E, int NB,
                                                  int* __restrict__ bcur,
                                                  unsigned* __restrict__ pairs) {
    __shared__ int cnt[512];
    __shared__ int lds_d[CH];
    int t = threadIdx.x;
    int e0 = blockIdx.x * CH;
    int e1 = e0 + CH; if (e1 > E) e1 = E;
    int n = e1 - e0;
    for (int b = t; b < 512; b += 256) cnt[b] = 0;
    __syncthreads();
    for (int i = t; i < n; i += 256) {
        int d = dst[e0 + i];
        lds_d[i] = d;
        atomicAdd(&cnt[d >> BSH], 1);
    }
    __syncthreads();
    for (int b = t; b < NB; b += 256) {
        int c = cnt[b];
        cnt[b] = c ? atomicAdd(&bcur[b], c) : 0;
    }
    __syncthreads();
    for (int i = t; i < n; i += 256) {
        int d = lds_d[i];
        int p = atomicAdd(&cnt[d >> BSH], 1);
        pairs[p] = ((unsigned)src[e0 + i] << BSH) | (unsigned)(d & (BSZ - 1));
    }
}

__global__ __launch_bounds__(256) void k_bucket(const int* __restrict__ boff,
                                                const unsigned* __restrict__ pairs,
                                                int N, int* __restrict__ rowptr,
                                                int* __restrict__ col) {
    __shared__ int cnt[BSZ];
    __shared__ int cur[BSZ];
    int t = threadIdx.x;
    int b = blockIdx.x;
    int dlo = b << BSH;
    int dhi = dlo + BSZ; if (dhi > N) dhi = N;
    int nd = dhi - dlo;
    int jb = boff[b], je = boff[b + 1];
    if (t < BSZ) cnt[t] = 0;
    __syncthreads();
    for (int j = jb + t; j < je; j += 256) atomicAdd(&cnt[pairs[j] & (BSZ - 1)], 1);
    __syncthreads();
    if (t < 64) {
        int v0 = cnt[t], v1 = cnt[64 + t];
        int i0 = v0;
#pragma unroll
        for (int off = 1; off < 64; off <<= 1) {
            int q = __shfl_up(i0, off, 64);
            if (t >= off) i0 += q;
        }
        int tot0 = __shfl(i0, 63, 64);
        int i1 = v1;
#pragma unroll
        for (int off = 1; off < 64; off <<= 1) {
            int q = __shfl_up(i1, off, 64);
            if (t >= off) i1 += q;
        }
        int e0x = jb + i0 - v0;
        int e1x = jb + tot0 + i1 - v1;
        cur[t] = e0x;
        cur[64 + t] = e1x;
        if (t < nd) rowptr[dlo + t] = e0x;
        if (64 + t < nd) rowptr[dlo + 64 + t] = e1x;
        if (t == 0 && dhi == N) rowptr[N] = je;
    }
    __syncthreads();
    for (int j = jb + t; j < je; j += 256) {
        unsigned pk = pairs[j];
        int p = atomicAdd(&cur[pk & (BSZ - 1)], 1);
        col[p] = (int)(pk >> BSH);
    }
}

// -------- weight convert/transpose to bf16 + sentinel init --------
__global__ __launch_bounds__(256) void k_cvtW(const float* __restrict__ W1,
                                              const float* __restrict__ W2,
                                              unsigned short* __restrict__ Wt1,
                                              unsigned short* __restrict__ Wt2,
                                              float* __restrict__ s1,
                                              float* __restrict__ s2,
                                              unsigned short* __restrict__ h1b,
                                              unsigned short* __restrict__ gb,
                                              int N) {
    int idx = blockIdx.x * 256 + threadIdx.x;
    if (idx < 16384) {
        int n = idx >> 8, k = idx & 255;
        Wt1[idx] = f2bf(W1[k * 64 + n]);
    } else if (idx < 16384 + 4096) {
        int j = idx - 16384;
        int n = j >> 6, k = j & 63;
        Wt2[j] = f2bf(W2[k * 64 + n]);
    } else if (idx < 20488) {
        s1[(size_t)N * 8 + (idx - 20480)] = -1e30f;       // asrc1 sentinel row
    } else if (idx == 20488) {
        s2[N] = -1e30f;                                    // asrc2 sentinel
    } else if (idx >= 20496 && idx < 20560) {
        h1b[(size_t)N * 64 + (idx - 20496)] = 0;           // Hb sentinel row = 0
    } else if (idx >= 20560 && idx < 20624) {
        gb[(size_t)N * 64 + (idx - 20560)] = 0;            // Gb sentinel row = 0
    }
}

// ---------------- MFMA GEMM1 ----------------
__global__ __launch_bounds__(256) void k_gemm1m(const float* __restrict__ X,
                                                const unsigned short* __restrict__ Wt,
                                                const float* __restrict__ atts,
                                                const float* __restrict__ attd,
                                                int N, unsigned short* __restrict__ Hb,
                                                float* __restrict__ asrc,
                                                float* __restrict__ adst) {
    __shared__ short Xl[64 * 256];
    int t = threadIdx.x, l = t & 63, w = t >> 6;
    int rblk = blockIdx.x * 64;

    int half = l >> 5;
    int c8 = (l & 31) * 8;
#pragma unroll
    for (int i = 0; i < 8; ++i) {
        int rl = w * 16 + i * 2 + half;
        int row = rblk + rl;
        float4 x0 = {0.f, 0.f, 0.f, 0.f}, x1 = {0.f, 0.f, 0.f, 0.f};
        if (row < N) {
            x0 = *reinterpret_cast<const float4*>(X + (size_t)row * 256 + c8);
            x1 = *reinterpret_cast<const float4*>(X + (size_t)row * 256 + c8 + 4);
        }
        bf16x8 p;
        p[0] = (short)f2bf(x0.x); p[1] = (short)f2bf(x0.y);
        p[2] = (short)f2bf(x0.z); p[3] = (short)f2bf(x0.w);
        p[4] = (short)f2bf(x1.x); p[5] = (short)f2bf(x1.y);
        p[6] = (short)f2bf(x1.z); p[7] = (short)f2bf(x1.w);
        int g = (l & 31) ^ (rl & 7);
        *reinterpret_cast<bf16x8*>(&Xl[rl * 256 + g * 8]) = p;
    }

    int m = l & 15, quad = l >> 4;
    int rl = w * 16 + m;
    f32x4 acc0 = {0.f, 0.f, 0.f, 0.f}, acc1 = acc0, acc2 = acc0, acc3 = acc0;
#pragma unroll
    for (int tt = 0; tt < 8; ++tt) {
        int g = (tt * 4 + quad) ^ (m & 7);
        bf16x8 a = *reinterpret_cast<const bf16x8*>(&Xl[rl * 256 + g * 8]);
        int kk = tt * 32 + quad * 8;
        bf16x8 b0 = *reinterpret_cast<const bf16x8*>(&Wt[(0 * 16 + m) * 256 + kk]);
        bf16x8 b1 = *reinterpret_cast<const bf16x8*>(&Wt[(1 * 16 + m) * 256 + kk]);
        bf16x8 b2 = *reinterpret_cast<const bf16x8*>(&Wt[(2 * 16 + m) * 256 + kk]);
        bf16x8 b3 = *reinterpret_cast<const bf16x8*>(&Wt[(3 * 16 + m) * 256 + kk]);
        acc0 = __builtin_amdgcn_mfma_f32_16x16x32_bf16(a, b0, acc0, 0, 0, 0);
        acc1 = __builtin_amdgcn_mfma_f32_16x16x32_bf16(a, b1, acc1, 0, 0, 0);
        acc2 = __builtin_amdgcn_mfma_f32_16x16x32_bf16(a, b2, acc2, 0, 0, 0);
        acc3 = __builtin_amdgcn_mfma_f32_16x16x32_bf16(a, b3, acc3, 0, 0, 0);
    }

    int r0 = rblk + w * 16;
    f32x4 accs[4] = {acc0, acc1, acc2, acc3};
#pragma unroll
    for (int nt = 0; nt < 4; ++nt) {
        int cn = nt * 16 + m;
        float av_s = atts[cn], av_d = attd[cn];
#pragma unroll
        for (int r = 0; r < 4; ++r) {
            int row = r0 + quad * 4 + r;
            float hv = accs[nt][r];
            if (row < N) Hb[(size_t)row * 64 + cn] = f2bf(hv);
            float vs = hv * av_s, vd = hv * av_d;
            vs += __shfl_xor(vs, 1, 64); vs += __shfl_xor(vs, 2, 64); vs += __shfl_xor(vs, 4, 64);
            vd += __shfl_xor(vd, 1, 64); vd += __shfl_xor(vd, 2, 64); vd += __shfl_xor(vd, 4, 64);
            if ((m & 7) == 0 && row < N) {
                int head = cn >> 3;
                asrc[row * 8 + head] = vs;
                adst[row * 8 + head] = vd;
            }
        }
    }
}

// ---------------- MFMA GEMM2 ----------------
__global__ __launch_bounds__(256) void k_gemm2m(const unsigned short* __restrict__ Xb,
                                                const unsigned short* __restrict__ Wt,
                                                const float* __restrict__ atts,
                                                const float* __restrict__ attd,
                                                int N, unsigned short* __restrict__ Gb,
                                                float* __restrict__ asrc,
                                                float* __restrict__ adst) {
    int t = threadIdx.x, l = t & 63, w = t >> 6;
    int rblk = blockIdx.x * 64;
    int m = l & 15, quad = l >> 4;
    int row = rblk + w * 16 + m;
    int rowc = (row < N) ? row : 0;

    f32x4 acc0 = {0.f, 0.f, 0.f, 0.f}, acc1 = acc0, acc2 = acc0, acc3 = acc0;
#pragma unroll
    for (int tt = 0; tt < 2; ++tt) {
        int kk = tt * 32 + quad * 8;
        bf16x8 a = *reinterpret_cast<const bf16x8*>(&Xb[(size_t)rowc * 64 + kk]);
        bf16x8 b0 = *reinterpret_cast<const bf16x8*>(&Wt[(0 * 16 + m) * 64 + kk]);
        bf16x8 b1 = *reinterpret_cast<const bf16x8*>(&Wt[(1 * 16 + m) * 64 + kk]);
        bf16x8 b2 = *reinterpret_cast<const bf16x8*>(&Wt[(2 * 16 + m) * 64 + kk]);
        bf16x8 b3 = *reinterpret_cast<const bf16x8*>(&Wt[(3 * 16 + m) * 64 + kk]);
        acc0 = __builtin_amdgcn_mfma_f32_16x16x32_bf16(a, b0, acc0, 0, 0, 0);
        acc1 = __builtin_amdgcn_mfma_f32_16x16x32_bf16(a, b1, acc1, 0, 0, 0);
        acc2 = __builtin_amdgcn_mfma_f32_16x16x32_bf16(a, b2, acc2, 0, 0, 0);
        acc3 = __builtin_amdgcn_mfma_f32_16x16x32_bf16(a, b3, acc3, 0, 0, 0);
    }

    int r0 = rblk + w * 16;
    f32x4 accs[4] = {acc0, acc1, acc2, acc3};
#pragma unroll
    for (int r = 0; r < 4; ++r) {
        int orow = r0 + quad * 4 + r;
        float vs = 0.f, vd = 0.f;
#pragma unroll
        for (int nt = 0; nt < 4; ++nt) {
            int cn = nt * 16 + m;
            float hv = accs[nt][r];
            if (orow < N) Gb[(size_t)orow * 64 + cn] = f2bf(hv);
            vs = fmaf(hv, atts[cn], vs);
            vd = fmaf(hv, attd[cn], vd);
        }
#pragma unroll
        for (int off = 1; off < 16; off <<= 1) {
            vs += __shfl_xor(vs, off, 64);
            vd += __shfl_xor(vd, off, 64);
        }
        if (m == 0 && orow < N) { asrc[orow] = vs; adst[orow] = vd; }
    }
}

// ------- Fused gather v3: LDS-staged col + 6-deep gather batch -------
// Block = 32 dsts, 32 groups of 8 lanes (1 dst/group, sub = head/ch-octet).
// col range for the block staged into LDS (coalesced, read once) -> inner
// loop has ONE global latency level: 6 asrc + 6 Hb gathers in flight.
// Tail edges via sentinel src row N (asrc=-1e30 -> w=0, Hb=0).

__global__ __launch_bounds__(256) void k_gather1(const int* __restrict__ rowptr,
                                                 const int* __restrict__ col,
                                                 const uint4* __restrict__ Hb8,
                                                 const float* __restrict__ asrc,
                                                 const float* __restrict__ adst,
                                                 const float* __restrict__ bias,
                                                 int N,
                                                 unsigned short* __restrict__ outb) {
    __shared__ int colS[ECH];
    int t = threadIdx.x;
    int gid = t >> 3, sub = t & 7;
    int d0 = blockIdx.x * 32;
    int dend = d0 + 32; if (dend > N) dend = N;
    int d = d0 + gid;
    int dok = (d < dend);
    int dc = dok ? d : d0;
    int jb = rowptr[dc];
    int je = rowptr[dc + 1];
    if (!dok) { jb = 0; je = 0; }
    float adv = dok ? adst[dc * 8 + sub] : 0.f;
    int ebeg = rowptr[d0];
    int eend = rowptr[dend];

    float acc[8] = {0.f, 0.f, 0.f, 0.f, 0.f, 0.f, 0.f, 0.f};
    float denom = 0.f;
    for (int cb = ebeg; cb < eend; cb += ECH) {
        int ce = cb + ECH; if (ce > eend) ce = eend;
        int n = ce - cb;
        __syncthreads();
        for (int i = t; i < n; i += 256) colS[i] = col[cb + i];
        __syncthreads();
        int lo = (jb > cb) ? jb : cb;
        int hi = (je < ce) ? je : ce;
        for (int u = lo; u < hi; u += GB) {
            int s6[GB];
#pragma unroll
            for (int q = 0; q < GB; ++q) {
                int uu = u + q;
                s6[q] = (uu < hi) ? colS[uu - cb] : N;   // sentinel: w=0, h=0
            }
            float as6[GB];
#pragma unroll
            for (int q = 0; q < GB; ++q) as6[q] = asrc[s6[q] * 8 + sub];
            uint4 hv6[GB];
#pragma unroll
            for (int q = 0; q < GB; ++q) hv6[q] = Hb8[(size_t)s6[q] * 8 + sub];
            __builtin_amdgcn_sched_barrier(0);
#pragma unroll
            for (int q = 0; q < GB; ++q) {
                float e = as6[q] + adv;
                e = (e > 0.f) ? e : LRELU * e;
                float wgt = __expf(e);
                uint4 hv = hv6[q];
                denom += wgt;
                acc[0] = fmaf(wgt, bf2f(hv.x & 0xffffu), acc[0]);
                acc[1] = fmaf(wgt, bf2f(hv.x >> 16), acc[1]);
                acc[2] = fmaf(wgt, bf2f(hv.y & 0xffffu), acc[2]);
                acc[3] = fmaf(wgt, bf2f(hv.y >> 16), acc[3]);
                acc[4] = fmaf(wgt, bf2f(hv.z & 0xffffu), acc[4]);
                acc[5] = fmaf(wgt, bf2f(hv.z >> 16), acc[5]);
                acc[6] = fmaf(wgt, bf2f(hv.w & 0xffffu), acc[6]);
                acc[7] = fmaf(wgt, bf2f(hv.w >> 16), acc[7]);
            }
        }
    }
    if (dok) {
        float invd = 1.f / (denom + 1e-16f);
        unsigned short pk[8];
#pragma unroll
        for (int c = 0; c < 8; ++c) {
            float v = fmaf(acc[c], invd, bias[sub * 8 + c]);
            v = (v > 0.f) ? v : expm1f(v);
            pk[c] = f2bf(v);
        }
        uint4 pv;
        pv.x = (unsigned)pk[0] | ((unsigned)pk[1] << 16);
        pv.y = (unsigned)pk[2] | ((unsigned)pk[3] << 16);
        pv.z = (unsigned)pk[4] | ((unsigned)pk[5] << 16);
        pv.w = (unsigned)pk[6] | ((unsigned)pk[7] << 16);
        *reinterpret_cast<uint4*>(&outb[(size_t)d * 64 + sub * 8]) = pv;
    }
}

__global__ __launch_bounds__(256) void k_gather2(const int* __restrict__ rowptr,
                                                 const int* __restrict__ col,
                                                 const uint4* __restrict__ Gb8,
                                                 const float* __restrict__ asrc,
                                                 const float* __restrict__ adst,
                                                 const float* __restrict__ bias,
                                                 int N,
                                                 float* __restrict__ out) {
    __shared__ int colS[ECH];
    int t = threadIdx.x;
    int gid = t >> 3, sub = t & 7;
    int d0 = blockIdx.x * 32;
    int dend = d0 + 32; if (dend > N) dend = N;
    int d = d0 + gid;
    int dok = (d < dend);
    int dc = dok ? d : d0;
    int jb = rowptr[dc];
    int je = rowptr[dc + 1];
    if (!dok) { jb = 0; je = 0; }
    float adv = dok ? adst[dc] : 0.f;
    int ebeg = rowptr[d0];
    int eend = rowptr[dend];

    float acc[8] = {0.f, 0.f, 0.f, 0.f, 0.f, 0.f, 0.f, 0.f};
    float denom = 0.f;
    for (int cb = ebeg; cb < eend; cb += ECH) {
        int ce = cb + ECH; if (ce > eend) ce = eend;
        int n = ce - cb;
        __syncthreads();
        for (int i = t; i < n; i += 256) colS[i] = col[cb + i];
        __syncthreads();
        int lo = (jb > cb) ? jb : cb;
        int hi = (je < ce) ? je : ce;
        for (int u = lo; u < hi; u += GB) {
            int s6[GB];
#pragma unroll
            for (int q = 0; q < GB; ++q) {
                int uu = u + q;
                s6[q] = (uu < hi) ? colS[uu - cb] : N;
            }
            float as6[GB];
#pragma unroll
            for (int q = 0; q < GB; ++q) as6[q] = asrc[s6[q]];
            uint4 hv6[GB];
#pragma unroll
            for (int q = 0; q < GB; ++q) hv6[q] = Gb8[(size_t)s6[q] * 8 + sub];
            __builtin_amdgcn_sched_barrier(0);
#pragma unroll
            for (int q = 0; q < GB; ++q) {
                float e = as6[q] + adv;
                e = (e > 0.f) ? e : LRELU * e;
                float wgt = __expf(e);
                uint4 hv = hv6[q];
                denom += wgt;
                acc[0] = fmaf(wgt, bf2f(hv.x & 0xffffu), acc[0]);
                acc[1] = fmaf(wgt, bf2f(hv.x >> 16), acc[1]);
                acc[2] = fmaf(wgt, bf2f(hv.y & 0xffffu), acc[2]);
                acc[3] = fmaf(wgt, bf2f(hv.y >> 16), acc[3]);
                acc[4] = fmaf(wgt, bf2f(hv.z & 0xffffu), acc[4]);
                acc[5] = fmaf(wgt, bf2f(hv.z >> 16), acc[5]);
                acc[6] = fmaf(wgt, bf2f(hv.w & 0xffffu), acc[6]);
                acc[7] = fmaf(wgt, bf2f(hv.w >> 16), acc[7]);
            }
        }
    }
    float invd = 1.f / (denom + 1e-16f);
    float v[8];
#pragma unroll
    for (int c = 0; c < 8; ++c) v[c] = fmaf(acc[c], invd, bias[sub * 8 + c]);
    // log_softmax over the 8-lane group (64 channels per dst)
    float m = v[0];
#pragma unroll
    for (int c = 1; c < 8; ++c) m = fmaxf(m, v[c]);
    m = fmaxf(m, __shfl_xor(m, 1, 64));
    m = fmaxf(m, __shfl_xor(m, 2, 64));
    m = fmaxf(m, __shfl_xor(m, 4, 64));
    float se = 0.f;
#pragma unroll
    for (int c = 0; c < 8; ++c) se += __expf(v[c] - m);
    se += __shfl_xor(se, 1, 64);
    se += __shfl_xor(se, 2, 64);
    se += __shfl_xor(se, 4, 64);
    float ls = m + __logf(se);
    if (dok) {
        float4 o0, o1;
        o0.x = v[0] - ls; o0.y = v[1] - ls; o0.z = v[2] - ls; o0.w = v[3] - ls;
        o1.x = v[4] - ls; o1.y = v[5] - ls; o1.z = v[6] - ls; o1.w = v[7] - ls;
        *reinterpret_cast<float4*>(&out[(size_t)d * 64 + sub * 8]) = o0;
        *reinterpret_cast<float4*>(&out[(size_t)d * 64 + sub * 8 + 4]) = o1;
    }
}

// ---------------- launch ----------------

extern "C" void kernel_launch(void* const* d_in, const int* in_sizes, int n_in,
                              void* d_out, int out_size, void* d_ws, size_t ws_size,
                              hipStream_t stream) {
    const float* x   = (const float*)d_in[0];
    const int*   ei  = (const int*)d_in[1];
    const float* W1  = (const float*)d_in[2];
    const float* as1 = (const float*)d_in[3];
    const float* ad1 = (const float*)d_in[4];
    const float* b1  = (const float*)d_in[5];
    const float* W2  = (const float*)d_in[6];
    const float* as2 = (const float*)d_in[7];
    const float* ad2 = (const float*)d_in[8];
    const float* b2  = (const float*)d_in[9];
    float* out = (float*)d_out;

    const int N = in_sizes[0] / 256;
    const int E = in_sizes[1] / 2;
    const int* src = ei;
    const int* dst = ei + E;
    const int NB = (N + BSZ - 1) >> BSH;
    const int nchunk = (E + CH - 1) / CH;

    char* ws = (char*)d_ws;
    size_t off = 0;
    auto alloc = [&](size_t bytes) -> void* {
        void* p = ws + off;
        off = (off + bytes + 255) & ~(size_t)255;
        return p;
    };
    int*      bcnt   = (int*)alloc((size_t)NB * 4);
    int*      boff   = (int*)alloc((size_t)(NB + 1) * 4);
    int*      bcur   = (int*)alloc((size_t)NB * 4);
    int*      rowptr = (int*)alloc((size_t)(N + 1) * 4);
    int*      col    = (int*)alloc((size_t)E * 4);
    unsigned* pairs  = (unsigned*)alloc((size_t)E * 4);
    unsigned short* wt1 = (unsigned short*)alloc(64 * 256 * 2);
    unsigned short* wt2 = (unsigned short*)alloc(64 * 64 * 2);
    unsigned short* h1b = (unsigned short*)alloc((size_t)(N + 1) * 64 * 2);
    float* a_s1   = (float*)alloc(((size_t)N * 8 + 8) * 4);
    float* a_d1   = (float*)alloc((size_t)N * 8 * 4);
    unsigned short* h2b = (unsigned short*)alloc((size_t)N * 64 * 2);
    unsigned short* gb  = (unsigned short*)alloc((size_t)(N + 1) * 64 * 2);
    float* a_s2   = (float*)alloc((size_t)(N + 1) * 4);
    float* a_d2   = (float*)alloc((size_t)N * 4);
    (void)ws_size; (void)n_in; (void)out_size;

    k_cvtW<<<81, 256, 0, stream>>>(W1, W2, wt1, wt2, a_s1, a_s2, h1b, gb, N);

    hipMemsetAsync(bcnt, 0, (size_t)NB * 4, stream);
    k_bcount<<<nchunk, 256, 0, stream>>>(dst, E, NB, bcnt);
    k_bscan<<<1, 64, 0, stream>>>(bcnt, NB, boff, bcur);
    k_binscat1<<<nchunk, 256, 0, stream>>>(src, dst, E, NB, bcur, pairs);
    k_bucket<<<NB, 256, 0, stream>>>(boff, pairs, N, rowptr, col);

    int gblk = (N + 63) / 64;
    k_gemm1m<<<gblk, 256, 0, stream>>>(x, wt1, as1, ad1, N, h1b, a_s1, a_d1);

    int gather_blocks = (N + 31) / 32;
    k_gather1<<<gather_blocks, 256, 0, stream>>>(rowptr, col, (const uint4*)h1b,
                                                 a_s1, a_d1, b1, N, h2b);

    k_gemm2m<<<gblk, 256, 0, stream>>>(h2b, wt2, as2, ad2, N, gb, a_s2, a_d2);

    k_gather2<<<gather_blocks, 256, 0, stream>>>(rowptr, col, (const uint4*)gb,
                                                 a_s2, a_d2, b2, N, out);
}

// Round 4
// 247.748 us; speedup vs baseline: 1.1541x; 1.0086x over previous
//
#include <hip/hip_runtime.h>
#include <math.h>

#define LRELU 0.2f
#define BSH 7                  // 128 dsts per bucket
#define BSZ (1 << BSH)
#define CH 8192                // edges per phase-1 block
#define ECH 2048               // staged edges per gather block (8 KB LDS)
#define GB 8                   // gather batch depth (loads in flight per lane)

typedef __attribute__((ext_vector_type(8))) short bf16x8;
typedef __attribute__((ext_vector_type(4))) float f32x4;

static __device__ __forceinline__ float bf2f(unsigned int u16) {
    union { unsigned int i; float f; } c; c.i = u16 << 16; return c.f;
}
static __device__ __forceinline__ unsigned short f2bf(float f) {
    union { float f; unsigned int i; } c; c.f = f;
    unsigned int x = c.i;
    return (unsigned short)((x + 0x7fffu + ((x >> 16) & 1u)) >> 16);  // RNE
}

// ---------------- prep: bucket-count chunks + weight cvt + sentinels ----------

__global__ __launch_bounds__(256) void k_prep(const int* __restrict__ dst, int E,
                                              int NB, int* __restrict__ bcnt,
                                              const float* __restrict__ W1,
                                              const float* __restrict__ W2,
                                              const float* __restrict__ as2in,
                                              const float* __restrict__ ad2in,
                                              unsigned short* __restrict__ Wt1,
                                              unsigned short* __restrict__ Wt2,
                                              float* __restrict__ s1,
                                              float* __restrict__ s2,
                                              unsigned short* __restrict__ h1b,
                                              unsigned short* __restrict__ gb,
                                              float* __restrict__ w2s,
                                              float* __restrict__ w2d,
                                              int N, int nchunk) {
    __shared__ int cnt[512];
    int t = threadIdx.x;
    if ((int)blockIdx.x < nchunk) {
        for (int b = t; b < 512; b += 256) cnt[b] = 0;
        __syncthreads();
        int e0 = blockIdx.x * CH;
        int e1 = e0 + CH; if (e1 > E) e1 = E;
        for (int i = e0 + t; i < e1; i += 256) atomicAdd(&cnt[dst[i] >> BSH], 1);
        __syncthreads();
        for (int b = t; b < NB; b += 256) {
            int c = cnt[b];
            if (c) atomicAdd(&bcnt[b], c);
        }
        return;
    }
    int idx = ((int)blockIdx.x - nchunk) * 256 + t;
    if (idx < 16384) {
        int n = idx >> 8, k = idx & 255;
        Wt1[idx] = f2bf(W1[k * 64 + n]);
    } else if (idx < 16384 + 4096) {
        int j = idx - 16384;
        int n = j >> 6, k = j & 63;
        Wt2[j] = f2bf(W2[k * 64 + n]);
    } else if (idx >= 20480 && idx < 20488) {
        s1[(size_t)N * 8 + (idx - 20480)] = -1e30f;       // asrc1 sentinel row
    } else if (idx == 20488) {
        s2[N] = -1e30f;                                    // asrc2 sentinel
    } else if (idx >= 20496 && idx < 20560) {
        h1b[(size_t)N * 64 + (idx - 20496)] = 0;           // Hb sentinel row = 0
    } else if (idx >= 20560 && idx < 20624) {
        gb[(size_t)N * 64 + (idx - 20560)] = 0;            // Gb sentinel row = 0
    } else if (idx >= 20624 && idx < 20688) {
        int c = idx - 20624;
        float s = 0.f;
#pragma unroll
        for (int n = 0; n < 64; ++n) s += W2[c * 64 + n] * as2in[n];
        w2s[c] = s;                                        // W2 @ att_src2
    } else if (idx >= 20688 && idx < 20752) {
        int c = idx - 20688;
        float s = 0.f;
#pragma unroll
        for (int n = 0; n < 64; ++n) s += W2[c * 64 + n] * ad2in[n];
        w2d[c] = s;                                        // W2 @ att_dst2
    }
}

__global__ __launch_bounds__(64) void k_bscan(const int* __restrict__ bcnt, int NB,
                                              int* __restrict__ boff,
                                              int* __restrict__ bcur) {
    int lane = threadIdx.x;
    int run = 0;
    for (int base = 0; base < NB; base += 64) {
        int v = (base + lane < NB) ? bcnt[base + lane] : 0;
        int inc = v;
#pragma unroll
        for (int off = 1; off < 64; off <<= 1) {
            int t = __shfl_up(inc, off, 64);
            if (lane >= off) inc += t;
        }
        if (base + lane < NB) {
            int e = run + inc - v;
            boff[base + lane] = e;
            bcur[base + lane] = e;
        }
        run += __shfl(inc, 63, 64);
    }
    if (lane == 0) boff[NB] = run;
}

__global__ __launch_bounds__(256) void k_binscat1(const int* __restrict__ src,
                                                  const int* __restrict__ dst,
                                                  int E, int NB,
                                                  int* __restrict__ bcur,
                                                  unsigned* __restrict__ pairs) {
    __shared__ int cnt[512];
    __shared__ int lds_d[CH];
    int t = threadIdx.x;
    int e0 = blockIdx.x * CH;
    int e1 = e0 + CH; if (e1 > E) e1 = E;
    int n = e1 - e0;
    for (int b = t; b < 512; b += 256) cnt[b] = 0;
    __syncthreads();
    for (int i = t; i < n; i += 256) {
        int d = dst[e0 + i];
        lds_d[i] = d;
        atomicAdd(&cnt[d >> BSH], 1);
    }
    __syncthreads();
    for (int b = t; b < NB; b += 256) {
        int c = cnt[b];
        cnt[b] = c ? atomicAdd(&bcur[b], c) : 0;
    }
    __syncthreads();
    for (int i = t; i < n; i += 256) {
        int d = lds_d[i];
        int p = atomicAdd(&cnt[d >> BSH], 1);
        pairs[p] = ((unsigned)src[e0 + i] << BSH) | (unsigned)(d & (BSZ - 1));
    }
}

__global__ __launch_bounds__(256) void k_bucket(const int* __restrict__ boff,
                                                const unsigned* __restrict__ pairs,
                                                int N, int* __restrict__ rowptr,
                                                int* __restrict__ col) {
    __shared__ int cnt[BSZ];
    __shared__ int cur[BSZ];
    int t = threadIdx.x;
    int b = blockIdx.x;
    int dlo = b << BSH;
    int dhi = dlo + BSZ; if (dhi > N) dhi = N;
    int nd = dhi - dlo;
    int jb = boff[b], je = boff[b + 1];
    if (t < BSZ) cnt[t] = 0;
    __syncthreads();
    for (int j = jb + t; j < je; j += 256) atomicAdd(&cnt[pairs[j] & (BSZ - 1)], 1);
    __syncthreads();
    if (t < 64) {
        int v0 = cnt[t], v1 = cnt[64 + t];
        int i0 = v0;
#pragma unroll
        for (int off = 1; off < 64; off <<= 1) {
            int q = __shfl_up(i0, off, 64);
            if (t >= off) i0 += q;
        }
        int tot0 = __shfl(i0, 63, 64);
        int i1 = v1;
#pragma unroll
        for (int off = 1; off < 64; off <<= 1) {
            int q = __shfl_up(i1, off, 64);
            if (t >= off) i1 += q;
        }
        int e0x = jb + i0 - v0;
        int e1x = jb + tot0 + i1 - v1;
        cur[t] = e0x;
        cur[64 + t] = e1x;
        if (t < nd) rowptr[dlo + t] = e0x;
        if (64 + t < nd) rowptr[dlo + 64 + t] = e1x;
        if (t == 0 && dhi == N) rowptr[N] = je;
    }
    __syncthreads();
    for (int j = jb + t; j < je; j += 256) {
        unsigned pk = pairs[j];
        int p = atomicAdd(&cur[pk & (BSZ - 1)], 1);
        col[p] = (int)(pk >> BSH);
    }
}

// ---------------- MFMA GEMM1 ----------------
__global__ __launch_bounds__(256) void k_gemm1m(const float* __restrict__ X,
                                                const unsigned short* __restrict__ Wt,
                                                const float* __restrict__ atts,
                                                const float* __restrict__ attd,
                                                int N, unsigned short* __restrict__ Hb,
                                                float* __restrict__ asrc,
                                                float* __restrict__ adst) {
    __shared__ short Xl[64 * 256];
    int t = threadIdx.x, l = t & 63, w = t >> 6;
    int rblk = blockIdx.x * 64;

    int half = l >> 5;
    int c8 = (l & 31) * 8;
#pragma unroll
    for (int i = 0; i < 8; ++i) {
        int rl = w * 16 + i * 2 + half;
        int row = rblk + rl;
        float4 x0 = {0.f, 0.f, 0.f, 0.f}, x1 = {0.f, 0.f, 0.f, 0.f};
        if (row < N) {
            x0 = *reinterpret_cast<const float4*>(X + (size_t)row * 256 + c8);
            x1 = *reinterpret_cast<const float4*>(X + (size_t)row * 256 + c8 + 4);
        }
        bf16x8 p;
        p[0] = (short)f2bf(x0.x); p[1] = (short)f2bf(x0.y);
        p[2] = (short)f2bf(x0.z); p[3] = (short)f2bf(x0.w);
        p[4] = (short)f2bf(x1.x); p[5] = (short)f2bf(x1.y);
        p[6] = (short)f2bf(x1.z); p[7] = (short)f2bf(x1.w);
        int g = (l & 31) ^ (rl & 7);
        *reinterpret_cast<bf16x8*>(&Xl[rl * 256 + g * 8]) = p;
    }

    int m = l & 15, quad = l >> 4;
    int rl = w * 16 + m;
    f32x4 acc0 = {0.f, 0.f, 0.f, 0.f}, acc1 = acc0, acc2 = acc0, acc3 = acc0;
#pragma unroll
    for (int tt = 0; tt < 8; ++tt) {
        int g = (tt * 4 + quad) ^ (m & 7);
        bf16x8 a = *reinterpret_cast<const bf16x8*>(&Xl[rl * 256 + g * 8]);
        int kk = tt * 32 + quad * 8;
        bf16x8 b0 = *reinterpret_cast<const bf16x8*>(&Wt[(0 * 16 + m) * 256 + kk]);
        bf16x8 b1 = *reinterpret_cast<const bf16x8*>(&Wt[(1 * 16 + m) * 256 + kk]);
        bf16x8 b2 = *reinterpret_cast<const bf16x8*>(&Wt[(2 * 16 + m) * 256 + kk]);
        bf16x8 b3 = *reinterpret_cast<const bf16x8*>(&Wt[(3 * 16 + m) * 256 + kk]);
        acc0 = __builtin_amdgcn_mfma_f32_16x16x32_bf16(a, b0, acc0, 0, 0, 0);
        acc1 = __builtin_amdgcn_mfma_f32_16x16x32_bf16(a, b1, acc1, 0, 0, 0);
        acc2 = __builtin_amdgcn_mfma_f32_16x16x32_bf16(a, b2, acc2, 0, 0, 0);
        acc3 = __builtin_amdgcn_mfma_f32_16x16x32_bf16(a, b3, acc3, 0, 0, 0);
    }

    int r0 = rblk + w * 16;
    f32x4 accs[4] = {acc0, acc1, acc2, acc3};
#pragma unroll
    for (int nt = 0; nt < 4; ++nt) {
        int cn = nt * 16 + m;
        float av_s = atts[cn], av_d = attd[cn];
#pragma unroll
        for (int r = 0; r < 4; ++r) {
            int row = r0 + quad * 4 + r;
            float hv = accs[nt][r];
            if (row < N) Hb[(size_t)row * 64 + cn] = f2bf(hv);
            float vs = hv * av_s, vd = hv * av_d;
            vs += __shfl_xor(vs, 1, 64); vs += __shfl_xor(vs, 2, 64); vs += __shfl_xor(vs, 4, 64);
            vd += __shfl_xor(vd, 1, 64); vd += __shfl_xor(vd, 2, 64); vd += __shfl_xor(vd, 4, 64);
            if ((m & 7) == 0 && row < N) {
                int head = cn >> 3;
                asrc[row * 8 + head] = vs;
                adst[row * 8 + head] = vd;
            }
        }
    }
}

// --- Fused gather1 + layer-2 GEMM: edge softmax-aggregate -> h2 (ELU) in LDS
//     -> 32x64 @ 64x64 MFMA -> Gb, plus as2/ad2 via precomputed w2s/w2d. ---
// Block = 32 dsts. lane group (8 lanes) owns one dst; sub = head/ch-octet.

__global__ __launch_bounds__(256) void k_gather1f(const int* __restrict__ rowptr,
                                                  const int* __restrict__ col,
                                                  const uint4* __restrict__ Hb8,
                                                  const float* __restrict__ asrc,
                                                  const float* __restrict__ adst,
                                                  const float* __restrict__ bias,
                                                  const unsigned short* __restrict__ Wt2,
                                                  const float* __restrict__ w2s,
                                                  const float* __restrict__ w2d,
                                                  int N,
                                                  unsigned short* __restrict__ Gb,
                                                  float* __restrict__ as2,
                                                  float* __restrict__ ad2) {
    __shared__ int colS[ECH];
    __shared__ short h2l[32 * 64];
    int t = threadIdx.x;
    int gid = t >> 3, sub = t & 7;
    int d0 = blockIdx.x * 32;
    int dend = d0 + 32; if (dend > N) dend = N;
    int d = d0 + gid;
    int dok = (d < dend);
    int dc = dok ? d : d0;
    int jb = rowptr[dc];
    int je = rowptr[dc + 1];
    if (!dok) { jb = 0; je = 0; }
    float adv = dok ? adst[dc * 8 + sub] : 0.f;
    int ebeg = rowptr[d0];
    int eend = rowptr[dend];

    float acc[8] = {0.f, 0.f, 0.f, 0.f, 0.f, 0.f, 0.f, 0.f};
    float denom = 0.f;
    for (int cb = ebeg; cb < eend; cb += ECH) {
        int ce = cb + ECH; if (ce > eend) ce = eend;
        int n = ce - cb;
        __syncthreads();
        for (int i = t; i < n; i += 256) colS[i] = col[cb + i];
        __syncthreads();
        int lo = (jb > cb) ? jb : cb;
        int hi = (je < ce) ? je : ce;
        for (int u = lo; u < hi; u += GB) {
            int s8[GB];
#pragma unroll
            for (int q = 0; q < GB; ++q) {
                int uu = u + q;
                s8[q] = (uu < hi) ? colS[uu - cb] : N;   // sentinel: w=0, h=0
            }
            float as8[GB];
#pragma unroll
            for (int q = 0; q < GB; ++q) as8[q] = asrc[s8[q] * 8 + sub];
            uint4 hv8[GB];
#pragma unroll
            for (int q = 0; q < GB; ++q) hv8[q] = Hb8[(size_t)s8[q] * 8 + sub];
            __builtin_amdgcn_sched_barrier(0);
#pragma unroll
            for (int q = 0; q < GB; ++q) {
                float e = as8[q] + adv;
                e = (e > 0.f) ? e : LRELU * e;
                float wgt = __expf(e);
                uint4 hv = hv8[q];
                denom += wgt;
                acc[0] = fmaf(wgt, bf2f(hv.x & 0xffffu), acc[0]);
                acc[1] = fmaf(wgt, bf2f(hv.x >> 16), acc[1]);
                acc[2] = fmaf(wgt, bf2f(hv.y & 0xffffu), acc[2]);
                acc[3] = fmaf(wgt, bf2f(hv.y >> 16), acc[3]);
                acc[4] = fmaf(wgt, bf2f(hv.z & 0xffffu), acc[4]);
                acc[5] = fmaf(wgt, bf2f(hv.z >> 16), acc[5]);
                acc[6] = fmaf(wgt, bf2f(hv.w & 0xffffu), acc[6]);
                acc[7] = fmaf(wgt, bf2f(hv.w >> 16), acc[7]);
            }
        }
    }

    // h2 = elu(agg/denom + bias1); as2/ad2 = h2 . (W2@att2) group-reduced
    float invd = 1.f / (denom + 1e-16f);
    float v[8];
#pragma unroll
    for (int c = 0; c < 8; ++c) {
        float x = fmaf(acc[c], invd, bias[sub * 8 + c]);
        v[c] = (x > 0.f) ? x : expm1f(x);
    }
    float vs = 0.f, vd = 0.f;
#pragma unroll
    for (int c = 0; c < 8; ++c) {
        vs = fmaf(v[c], w2s[sub * 8 + c], vs);
        vd = fmaf(v[c], w2d[sub * 8 + c], vd);
    }
    vs += __shfl_xor(vs, 1, 64); vs += __shfl_xor(vs, 2, 64); vs += __shfl_xor(vs, 4, 64);
    vd += __shfl_xor(vd, 1, 64); vd += __shfl_xor(vd, 2, 64); vd += __shfl_xor(vd, 4, 64);
    if (dok && sub == 0) { as2[d] = vs; ad2[d] = vd; }

    // stage h2 bf16 into LDS, octet XOR-swizzled (row r, octet o at o^(r&7))
    bf16x8 p;
#pragma unroll
    for (int c = 0; c < 8; ++c) p[c] = (short)f2bf(v[c]);
    *reinterpret_cast<bf16x8*>(&h2l[gid * 64 + (sub ^ (gid & 7)) * 8]) = p;
    __syncthreads();

    // 32x64 = h2l(32x64) @ W2(64x64), 16x16x32 MFMA, 4 waves x (1 Mtile x 2 Ntiles)
    int l = t & 63, w = t >> 6;
    int m = l & 15, quad = l >> 4;
    int mt = w & 1;
    int ntb = (w >> 1) * 2;
    int r = mt * 16 + m;
    f32x4 g0 = {0.f, 0.f, 0.f, 0.f}, g1 = g0;
#pragma unroll
    for (int tt = 0; tt < 2; ++tt) {
        bf16x8 a = *reinterpret_cast<const bf16x8*>(
            &h2l[r * 64 + ((tt * 4 + quad) ^ (r & 7)) * 8]);
        int kk = tt * 32 + quad * 8;
        bf16x8 b0 = *reinterpret_cast<const bf16x8*>(&Wt2[((ntb + 0) * 16 + m) * 64 + kk]);
        bf16x8 b1 = *reinterpret_cast<const bf16x8*>(&Wt2[((ntb + 1) * 16 + m) * 64 + kk]);
        g0 = __builtin_amdgcn_mfma_f32_16x16x32_bf16(a, b0, g0, 0, 0, 0);
        g1 = __builtin_amdgcn_mfma_f32_16x16x32_bf16(a, b1, g1, 0, 0, 0);
    }
    f32x4 gs[2] = {g0, g1};
#pragma unroll
    for (int nt = 0; nt < 2; ++nt) {
        int cn = (ntb + nt) * 16 + m;
#pragma unroll
        for (int rr = 0; rr < 4; ++rr) {
            int dr = d0 + mt * 16 + quad * 4 + rr;
            if (dr < N) Gb[(size_t)dr * 64 + cn] = f2bf(gs[nt][rr]);
        }
    }
}

__global__ __launch_bounds__(256) void k_gather2(const int* __restrict__ rowptr,
                                                 const int* __restrict__ col,
                                                 const uint4* __restrict__ Gb8,
                                                 const float* __restrict__ asrc,
                                                 const float* __restrict__ adst,
                                                 const float* __restrict__ bias,
                                                 int N,
                                                 float* __restrict__ out) {
    __shared__ int colS[ECH];
    int t = threadIdx.x;
    int gid = t >> 3, sub = t & 7;
    int d0 = blockIdx.x * 32;
    int dend = d0 + 32; if (dend > N) dend = N;
    int d = d0 + gid;
    int dok = (d < dend);
    int dc = dok ? d : d0;
    int jb = rowptr[dc];
    int je = rowptr[dc + 1];
    if (!dok) { jb = 0; je = 0; }
    float adv = dok ? adst[dc] : 0.f;
    int ebeg = rowptr[d0];
    int eend = rowptr[dend];

    float acc[8] = {0.f, 0.f, 0.f, 0.f, 0.f, 0.f, 0.f, 0.f};
    float denom = 0.f;
    for (int cb = ebeg; cb < eend; cb += ECH) {
        int ce = cb + ECH; if (ce > eend) ce = eend;
        int n = ce - cb;
        __syncthreads();
        for (int i = t; i < n; i += 256) colS[i] = col[cb + i];
        __syncthreads();
        int lo = (jb > cb) ? jb : cb;
        int hi = (je < ce) ? je : ce;
        for (int u = lo; u < hi; u += GB) {
            int s8[GB];
#pragma unroll
            for (int q = 0; q < GB; ++q) {
                int uu = u + q;
                s8[q] = (uu < hi) ? colS[uu - cb] : N;
            }
            float as8[GB];
#pragma unroll
            for (int q = 0; q < GB; ++q) as8[q] = asrc[s8[q]];
            uint4 hv8[GB];
#pragma unroll
            for (int q = 0; q < GB; ++q) hv8[q] = Gb8[(size_t)s8[q] * 8 + sub];
            __builtin_amdgcn_sched_barrier(0);
#pragma unroll
            for (int q = 0; q < GB; ++q) {
                float e = as8[q] + adv;
                e = (e > 0.f) ? e : LRELU * e;
                float wgt = __expf(e);
                uint4 hv = hv8[q];
                denom += wgt;
                acc[0] = fmaf(wgt, bf2f(hv.x & 0xffffu), acc[0]);
                acc[1] = fmaf(wgt, bf2f(hv.x >> 16), acc[1]);
                acc[2] = fmaf(wgt, bf2f(hv.y & 0xffffu), acc[2]);
                acc[3] = fmaf(wgt, bf2f(hv.y >> 16), acc[3]);
                acc[4] = fmaf(wgt, bf2f(hv.z & 0xffffu), acc[4]);
                acc[5] = fmaf(wgt, bf2f(hv.z >> 16), acc[5]);
                acc[6] = fmaf(wgt, bf2f(hv.w & 0xffffu), acc[6]);
                acc[7] = fmaf(wgt, bf2f(hv.w >> 16), acc[7]);
            }
        }
    }
    float invd = 1.f / (denom + 1e-16f);
    float v[8];
#pragma unroll
    for (int c = 0; c < 8; ++c) v[c] = fmaf(acc[c], invd, bias[sub * 8 + c]);
    // log_softmax over the 8-lane group (64 channels per dst)
    float m = v[0];
#pragma unroll
    for (int c = 1; c < 8; ++c) m = fmaxf(m, v[c]);
    m = fmaxf(m, __shfl_xor(m, 1, 64));
    m = fmaxf(m, __shfl_xor(m, 2, 64));
    m = fmaxf(m, __shfl_xor(m, 4, 64));
    float se = 0.f;
#pragma unroll
    for (int c = 0; c < 8; ++c) se += __expf(v[c] - m);
    se += __shfl_xor(se, 1, 64);
    se += __shfl_xor(se, 2, 64);
    se += __shfl_xor(se, 4, 64);
    float ls = m + __logf(se);
    if (dok) {
        float4 o0, o1;
        o0.x = v[0] - ls; o0.y = v[1] - ls; o0.z = v[2] - ls; o0.w = v[3] - ls;
        o1.x = v[4] - ls; o1.y = v[5] - ls; o1.z = v[6] - ls; o1.w = v[7] - ls;
        *reinterpret_cast<float4*>(&out[(size_t)d * 64 + sub * 8]) = o0;
        *reinterpret_cast<float4*>(&out[(size_t)d * 64 + sub * 8 + 4]) = o1;
    }
}

// ---------------- launch ----------------

extern "C" void kernel_launch(void* const* d_in, const int* in_sizes, int n_in,
                              void* d_out, int out_size, void* d_ws, size_t ws_size,
                              hipStream_t stream) {
    const float* x   = (const float*)d_in[0];
    const int*   ei  = (const int*)d_in[1];
    const float* W1  = (const float*)d_in[2];
    const float* as1 = (const float*)d_in[3];
    const float* ad1 = (const float*)d_in[4];
    const float* b1  = (const float*)d_in[5];
    const float* W2  = (const float*)d_in[6];
    const float* as2 = (const float*)d_in[7];
    const float* ad2 = (const float*)d_in[8];
    const float* b2  = (const float*)d_in[9];
    float* out = (float*)d_out;

    const int N = in_sizes[0] / 256;
    const int E = in_sizes[1] / 2;
    const int* src = ei;
    const int* dst = ei + E;
    const int NB = (N + BSZ - 1) >> BSH;
    const int nchunk = (E + CH - 1) / CH;

    char* ws = (char*)d_ws;
    size_t off = 0;
    auto alloc = [&](size_t bytes) -> void* {
        void* p = ws + off;
        off = (off + bytes + 255) & ~(size_t)255;
        return p;
    };
    int*      bcnt   = (int*)alloc((size_t)NB * 4);
    int*      boff   = (int*)alloc((size_t)(NB + 1) * 4);
    int*      bcur   = (int*)alloc((size_t)NB * 4);
    int*      rowptr = (int*)alloc((size_t)(N + 1) * 4);
    int*      col    = (int*)alloc((size_t)E * 4);
    unsigned* pairs  = (unsigned*)alloc((size_t)E * 4);
    unsigned short* wt1 = (unsigned short*)alloc(64 * 256 * 2);
    unsigned short* wt2 = (unsigned short*)alloc(64 * 64 * 2);
    unsigned short* h1b = (unsigned short*)alloc((size_t)(N + 1) * 64 * 2);
    float* a_s1   = (float*)alloc(((size_t)N * 8 + 8) * 4);
    float* a_d1   = (float*)alloc((size_t)N * 8 * 4);
    unsigned short* gb  = (unsigned short*)alloc((size_t)(N + 1) * 64 * 2);
    float* a_s2   = (float*)alloc((size_t)(N + 1) * 4);
    float* a_d2   = (float*)alloc((size_t)N * 4);
    float* w2s    = (float*)alloc(64 * 4);
    float* w2d    = (float*)alloc(64 * 4);
    (void)ws_size; (void)n_in; (void)out_size;

    hipMemsetAsync(bcnt, 0, (size_t)NB * 4, stream);
    k_prep<<<nchunk + 82, 256, 0, stream>>>(dst, E, NB, bcnt, W1, W2, as2, ad2,
                                            wt1, wt2, a_s1, a_s2, h1b, gb,
                                            w2s, w2d, N, nchunk);
    k_bscan<<<1, 64, 0, stream>>>(bcnt, NB, boff, bcur);
    k_binscat1<<<nchunk, 256, 0, stream>>>(src, dst, E, NB, bcur, pairs);
    k_bucket<<<NB, 256, 0, stream>>>(boff, pairs, N, rowptr, col);

    int gblk = (N + 63) / 64;
    k_gemm1m<<<gblk, 256, 0, stream>>>(x, wt1, as1, ad1, N, h1b, a_s1, a_d1);

    int gather_blocks = (N + 31) / 32;
    k_gather1f<<<gather_blocks, 256, 0, stream>>>(rowptr, col, (const uint4*)h1b,
                                                  a_s1, a_d1, b1, wt2, w2s, w2d,
                                                  N, gb, a_s2, a_d2);

    k_gather2<<<gather_blocks, 256, 0, stream>>>(rowptr, col, (const uint4*)gb,
                                                 a_s2, a_d2, b2, N, out);
}